// Round 1
// baseline (508.587 us; speedup 1.0000x reference)
//
#include <hip/hip_runtime.h>
#include <math.h>

#define NB 32
#define NP 24656
#define NO 16
#define NC 81
#define ND 85   // 4 + NC
#define THRESH_F 0.5f
#define NEGPOS_I 3
#define VAR0_F 0.1f
#define VAR1_F 0.2f

#define BPCNT (NB * NP)

// ---------------------------------------------------------------- init
__global__ void k_init(unsigned long long* __restrict__ bpk,
                       int* __restrict__ npos,
                       float* __restrict__ acc) {
    int t = blockIdx.x * blockDim.x + threadIdx.x;
    if (t < NB * NO) bpk[t] = 0ull;
    if (t < NB) npos[t] = 0;
    if (t < 2) acc[t] = 0.f;
}

// ---------------------------------------------------------------- match
// per (b,p): best truth over O (first-max tie); per (b,o): argmax over P via
// packed key (value_bits<<32 | ~p) so max key == max value then min index.
__global__ __launch_bounds__(256) void k_match(
    const float* __restrict__ tboxes, const float* __restrict__ priors,
    float* __restrict__ bto, int* __restrict__ bti,
    unsigned long long* __restrict__ bpk) {
    const int b = blockIdx.y;
    const int p = blockIdx.x * 256 + threadIdx.x;
    __shared__ float tb[NO * 4];
    if (threadIdx.x < NO * 4) tb[threadIdx.x] = tboxes[b * NO * 4 + threadIdx.x];
    __syncthreads();

    const bool valid = (p < NP);
    float4 pr = make_float4(0.f, 0.f, 1.f, 1.f);
    if (valid) pr = *(const float4*)(priors + (size_t)p * 4);
    const float pl = pr.x - pr.z * 0.5f, pt = pr.y - pr.w * 0.5f;
    const float prr = pr.x + pr.z * 0.5f, pb = pr.y + pr.w * 0.5f;
    const float parea = (prr - pl) * (pb - pt);

    float bestv = -1.f;
    int besti = 0;
    for (int o = 0; o < NO; ++o) {
        const float al = tb[o * 4 + 0], at = tb[o * 4 + 1];
        const float ar = tb[o * 4 + 2], ab = tb[o * 4 + 3];
        float iw = fminf(ar, prr) - fmaxf(al, pl); iw = fmaxf(iw, 0.f);
        float ih = fminf(ab, pb) - fmaxf(at, pt); ih = fmaxf(ih, 0.f);
        const float inter = iw * ih;
        const float aarea = (ar - al) * (ab - at);
        float iou = inter / (aarea + parea - inter);
        if (!valid) iou = -1.f;
        if (iou > bestv) { bestv = iou; besti = o; }

        unsigned long long key = 0ull;
        if (valid)
            key = ((unsigned long long)__float_as_uint(iou) << 32) |
                  (unsigned long long)(0xFFFFFFFFu - (unsigned)p);
        for (int s = 32; s > 0; s >>= 1) {
            unsigned long long other = __shfl_down(key, s, 64);
            if (other > key) key = other;
        }
        if ((threadIdx.x & 63) == 0) atomicMax(&bpk[b * NO + o], key);
    }
    if (valid) {
        bto[(size_t)b * NP + p] = bestv;
        bti[(size_t)b * NP + p] = besti;
    }
}

// ---------------------------------------------------------------- scatter
// best_truth_ov[best_prior_idx[o]] = 2, best_truth_idx[...] = o; last o wins.
__global__ void k_scatter(const unsigned long long* __restrict__ bpk,
                          float* __restrict__ bto, int* __restrict__ bti) {
    int b = blockIdx.x * blockDim.x + threadIdx.x;
    if (b >= NB) return;
    for (int o = 0; o < NO; ++o) {
        unsigned long long key = bpk[b * NO + o];
        int p = (int)(0xFFFFFFFFu - (unsigned)(key & 0xFFFFFFFFull));
        bto[(size_t)b * NP + p] = 2.0f;
        bti[(size_t)b * NP + p] = o;
    }
}

// ---------------------------------------------------------------- main fused
// One wave per 64 priors: stage 64x85 f32 rows into LDS (coalesced float4),
// then per-lane: log-softmax CE, conf_t, encode + smooth-L1, loss_rank.
__global__ __launch_bounds__(64) void k_main(
    const float* __restrict__ pred, const float* __restrict__ tboxes,
    const int* __restrict__ tlabels, const float* __restrict__ priors,
    const float* __restrict__ bto, const int* __restrict__ bti,
    float* __restrict__ lr, int* __restrict__ npos, float* __restrict__ acc) {
    __shared__ float rows[64 * ND];
    __shared__ float tb[NO * 4];
    __shared__ int tl[NO];

    const int b = blockIdx.y;
    const int p0 = blockIdx.x * 64;
    const int lane = threadIdx.x;
    const int valid = min(64, NP - p0);

    if (lane < NO * 4) tb[lane] = tboxes[b * NO * 4 + lane];
    if (lane < NO) tl[lane] = tlabels[b * NO + lane];

    // stage: base is 16B-aligned since (b*NP + 64*blk) % 4 == 0
    const float4* src = (const float4*)(pred + ((size_t)b * NP + p0) * ND);
    float4* dst = (float4*)rows;
    const int nf4 = valid * ND / 4;
    for (int i = lane; i < nf4; i += 64) dst[i] = src[i];
    __syncthreads();

    float my_ll = 0.f, my_ce_pos = 0.f;
    int my_pos = 0;
    const int p = p0 + lane;
    if (lane < valid) {
        const float* row = rows + lane * ND;
        float m = row[4];
        for (int c = 1; c < NC; ++c) m = fmaxf(m, row[4 + c]);
        float s = 0.f;
        for (int c = 0; c < NC; ++c) s += __expf(row[4 + c] - m);
        const float lse = m + __logf(s);

        const float btv = bto[(size_t)b * NP + p];
        const int o = bti[(size_t)b * NP + p];
        const bool pos = (btv >= THRESH_F);
        const int lbl = pos ? (tl[o] + 1) : 0;
        const float ce = lse - row[4 + lbl];
        lr[(size_t)b * NP + p] = pos ? 0.f : ce;

        if (pos) {
            my_ce_pos = ce;
            my_pos = 1;
            const float4 pr = *(const float4*)(priors + (size_t)p * 4);
            const float mx0 = tb[o * 4 + 0], my0 = tb[o * 4 + 1];
            const float mx1 = tb[o * 4 + 2], my1 = tb[o * 4 + 3];
            float lt0 = ((mx0 + mx1) * 0.5f - pr.x) / (VAR0_F * pr.z);
            float lt1 = ((my0 + my1) * 0.5f - pr.y) / (VAR0_F * pr.w);
            float lt2 = __logf((mx1 - mx0) / pr.z) / VAR1_F;
            float lt3 = __logf((my1 - my0) / pr.w) / VAR1_F;
            float ltv[4] = {lt0, lt1, lt2, lt3};
            for (int j = 0; j < 4; ++j) {
                float d = row[j] - ltv[j];
                float ad = fabsf(d);
                my_ll += (ad < 1.f) ? 0.5f * d * d : (ad - 0.5f);
            }
        }
    }
    for (int s = 32; s > 0; s >>= 1) {
        my_ll += __shfl_down(my_ll, s, 64);
        my_ce_pos += __shfl_down(my_ce_pos, s, 64);
        my_pos += __shfl_down(my_pos, s, 64);
    }
    if (lane == 0) {
        if (my_ll != 0.f) atomicAdd(&acc[0], my_ll);
        if (my_ce_pos != 0.f) atomicAdd(&acc[1], my_ce_pos);
        if (my_pos) atomicAdd(&npos[b], my_pos);
    }
}

// ---------------------------------------------------------------- select
// per b: radix-select the K-th largest loss_rank value T (uint bits, all >= 0),
// then negatives-sum = sum(v > T) + (K - cnt(v > T)) * T. Exact under ties.
__global__ __launch_bounds__(256) void k_select(
    const float* __restrict__ lrk, const int* __restrict__ npos,
    float* __restrict__ acc) {
    const int b = blockIdx.x;
    const float* row = lrk + (size_t)b * NP;
    __shared__ unsigned hist[256];
    __shared__ int sh_bucket;
    __shared__ int sh_knew;

    const int K0 = min(npos[b] * NEGPOS_I, NP);
    int k = K0;
    unsigned prefix = 0;
    for (int shift = 24; shift >= 0; shift -= 8) {
        for (int i = threadIdx.x; i < 256; i += blockDim.x) hist[i] = 0;
        __syncthreads();
        const unsigned mask_hi = (shift == 24) ? 0u : (0xFFFFFFFFu << (shift + 8));
        for (int i = threadIdx.x; i < NP; i += blockDim.x) {
            unsigned v = __float_as_uint(row[i]);
            if ((v & mask_hi) == (prefix & mask_hi))
                atomicAdd(&hist[(v >> shift) & 0xFFu], 1u);
        }
        __syncthreads();
        if (threadIdx.x == 0) {
            int cum = 0, bsel = 0, kn = k;
            for (int bb = 255; bb >= 0; --bb) {
                int c = (int)hist[bb];
                if (cum + c >= k) { bsel = bb; kn = k - cum; break; }
                cum += c;
            }
            sh_bucket = bsel;
            sh_knew = kn;
        }
        __syncthreads();
        prefix |= ((unsigned)sh_bucket) << shift;
        k = sh_knew;
        __syncthreads();
    }
    const float T = __uint_as_float(prefix);

    float msum = 0.f;
    int mcnt = 0;
    for (int i = threadIdx.x; i < NP; i += blockDim.x) {
        float v = row[i];
        if (__float_as_uint(v) > prefix) { msum += v; mcnt++; }
    }
    for (int s = 32; s > 0; s >>= 1) {
        msum += __shfl_down(msum, s, 64);
        mcnt += __shfl_down(mcnt, s, 64);
    }
    __shared__ float wsum[4];
    __shared__ int wcnt[4];
    const int wid = threadIdx.x >> 6;
    if ((threadIdx.x & 63) == 0) { wsum[wid] = msum; wcnt[wid] = mcnt; }
    __syncthreads();
    if (threadIdx.x == 0) {
        float tot = 0.f;
        int cnt = 0;
        for (int wI = 0; wI < 4; ++wI) { tot += wsum[wI]; cnt += wcnt[wI]; }
        float negsum = tot + (float)(K0 - cnt) * T;
        atomicAdd(&acc[1], negsum);
    }
}

// ---------------------------------------------------------------- final
__global__ void k_final(const int* __restrict__ npos,
                        const float* __restrict__ acc,
                        float* __restrict__ out) {
    if (threadIdx.x == 0 && blockIdx.x == 0) {
        int n = 0;
        for (int b = 0; b < NB; ++b) n += npos[b];
        const float N = (float)n;
        out[0] = acc[0] / N;
        out[1] = acc[1] / N;
    }
}

extern "C" void kernel_launch(void* const* d_in, const int* in_sizes, int n_in,
                              void* d_out, int out_size, void* d_ws, size_t ws_size,
                              hipStream_t stream) {
    const float* pred   = (const float*)d_in[0];
    const float* tboxes = (const float*)d_in[1];
    const int*   tlabels = (const int*)d_in[2];
    const float* priors = (const float*)d_in[3];
    float* out = (float*)d_out;

    char* w = (char*)d_ws;
    float* bto = (float*)w;                                   // BPCNT f32
    int*   bti = (int*)(w + 4ull * BPCNT);                    // BPCNT i32
    float* lrk = (float*)(w + 8ull * BPCNT);                  // BPCNT f32
    unsigned long long* bpk =
        (unsigned long long*)(w + 12ull * BPCNT);             // NB*NO u64 (8B-aligned)
    int* npos = (int*)(w + 12ull * BPCNT + 8ull * NB * NO);   // NB i32
    float* acc = (float*)(w + 12ull * BPCNT + 8ull * NB * NO + 4ull * NB); // 2 f32

    k_init<<<dim3(2), dim3(256), 0, stream>>>(bpk, npos, acc);
    k_match<<<dim3((NP + 255) / 256, NB), dim3(256), 0, stream>>>(
        tboxes, priors, bto, bti, bpk);
    k_scatter<<<dim3(1), dim3(64), 0, stream>>>(bpk, bto, bti);
    k_main<<<dim3((NP + 63) / 64, NB), dim3(64), 0, stream>>>(
        pred, tboxes, tlabels, priors, bto, bti, lrk, npos, acc);
    k_select<<<dim3(NB), dim3(256), 0, stream>>>(lrk, npos, acc);
    k_final<<<dim3(1), dim3(1), 0, stream>>>(npos, acc, out);
}

// Round 2
// 455.425 us; speedup vs baseline: 1.1167x; 1.1167x over previous
//
#include <hip/hip_runtime.h>
#include <math.h>

#define NB 32
#define NP 24656
#define NO 16
#define NC 81
#define ND 85   // 4 + NC
#define THRESH_F 0.5f
#define NEGPOS_I 3
#define VAR0_F 0.1f
#define VAR1_F 0.2f

#define BPCNT (NB * NP)
#define WPB 256          // waves per batch row in k_main
#define CHUNK ((NP + WPB - 1) / WPB)   // 97 rows per wave

// ---------------------------------------------------------------- init
__global__ void k_init(unsigned long long* __restrict__ bpk,
                       int* __restrict__ npos,
                       float* __restrict__ acc) {
    int t = blockIdx.x * blockDim.x + threadIdx.x;
    if (t < NB * NO) bpk[t] = 0ull;
    if (t < NB) npos[t] = 0;
    if (t < 2) acc[t] = 0.f;
}

// ---------------------------------------------------------------- match
// per (b,p): best truth over O (first-max tie); per (b,o): argmax over P via
// f32 wave-max + ballot (lowest lane = lowest p), then one u64 atomicMax
// with key (value_bits<<32 | ~p) per wave.
__global__ __launch_bounds__(256) void k_match(
    const float* __restrict__ tboxes, const float* __restrict__ priors,
    float* __restrict__ bto, int* __restrict__ bti,
    unsigned long long* __restrict__ bpk) {
    const int b = blockIdx.y;
    const int p = blockIdx.x * 256 + threadIdx.x;
    const int lane = threadIdx.x & 63;
    __shared__ float tb[NO * 4];
    if (threadIdx.x < NO * 4) tb[threadIdx.x] = tboxes[b * NO * 4 + threadIdx.x];
    __syncthreads();

    const bool valid = (p < NP);
    float4 pr = make_float4(0.f, 0.f, 1.f, 1.f);
    if (valid) pr = *(const float4*)(priors + (size_t)p * 4);
    const float pl = pr.x - pr.z * 0.5f, pt = pr.y - pr.w * 0.5f;
    const float prr = pr.x + pr.z * 0.5f, pb = pr.y + pr.w * 0.5f;
    const float parea = (prr - pl) * (pb - pt);

    float bestv = -1.f;
    int besti = 0;
    for (int o = 0; o < NO; ++o) {
        const float al = tb[o * 4 + 0], at = tb[o * 4 + 1];
        const float ar = tb[o * 4 + 2], ab = tb[o * 4 + 3];
        float iw = fminf(ar, prr) - fmaxf(al, pl); iw = fmaxf(iw, 0.f);
        float ih = fminf(ab, pb) - fmaxf(at, pt); ih = fmaxf(ih, 0.f);
        const float inter = iw * ih;
        const float aarea = (ar - al) * (ab - at);
        float iou = inter / (aarea + parea - inter);
        if (!valid) iou = -1.f;
        if (iou > bestv) { bestv = iou; besti = o; }

        float m = iou;
        for (int d = 1; d < 64; d <<= 1) m = fmaxf(m, __shfl_xor(m, d, 64));
        if (m >= 0.f) {  // wave has at least one valid lane
            unsigned long long msk = __ballot(iou == m);
            int lam = __ffsll(msk) - 1;
            int pw = blockIdx.x * 256 + (threadIdx.x & ~63) + lam;
            if (lane == 0) {
                unsigned long long key =
                    ((unsigned long long)__float_as_uint(m) << 32) |
                    (unsigned long long)(0xFFFFFFFFu - (unsigned)pw);
                atomicMax(&bpk[b * NO + o], key);
            }
        }
    }
    if (valid) {
        bto[(size_t)b * NP + p] = bestv;
        bti[(size_t)b * NP + p] = besti;
    }
}

// ---------------------------------------------------------------- scatter
__global__ void k_scatter(const unsigned long long* __restrict__ bpk,
                          float* __restrict__ bto, int* __restrict__ bti) {
    int b = blockIdx.x * blockDim.x + threadIdx.x;
    if (b >= NB) return;
    for (int o = 0; o < NO; ++o) {
        unsigned long long key = bpk[b * NO + o];
        int p = (int)(0xFFFFFFFFu - (unsigned)(key & 0xFFFFFFFFull));
        bto[(size_t)b * NP + p] = 2.0f;
        bti[(size_t)b * NP + p] = o;
    }
}

// ---------------------------------------------------------------- main fused
// Wave-per-row: wave reads one 85-float row coalesced (row[lane], row[64+lane]),
// softmax via 6-step shfl_xor reductions; ce/encode/sl1 are wave-uniform.
// Next-row prefetch; lr written coalesced per 64-row group.
__global__ __launch_bounds__(256) void k_main(
    const float* __restrict__ pred, const float* __restrict__ tboxes,
    const int* __restrict__ tlabels, const float* __restrict__ priors,
    const float* __restrict__ bto, const int* __restrict__ bti,
    float* __restrict__ lr, int* __restrict__ npos, float* __restrict__ acc) {
    __shared__ float tb[NO * 4];
    __shared__ int tl[NO];

    const int b = blockIdx.y;
    const int lane = threadIdx.x & 63;
    const int wid_in_b = blockIdx.x * 4 + (threadIdx.x >> 6);  // 0..WPB-1

    if (threadIdx.x < NO * 4) tb[threadIdx.x] = tboxes[b * NO * 4 + threadIdx.x];
    if (threadIdx.x < NO) tl[threadIdx.x] = tlabels[b * NO + threadIdx.x];
    __syncthreads();

    const int r0 = wid_in_b * CHUNK;
    const int r1 = min(r0 + CHUNK, NP);
    if (r0 >= NP) return;

    const size_t bbase = (size_t)b * NP;
    const float* base = pred + bbase * ND;

    float acc_ll = 0.f, acc_ce = 0.f;
    int acc_np = 0;

    // prefetch first row
    float p0v = base[(size_t)r0 * ND + lane];
    float p1v = (lane < ND - 64) ? base[(size_t)r0 * ND + 64 + lane] : -1e30f;

    for (int g0 = r0; g0 < r1; g0 += 64) {
        const int gn = min(64, r1 - g0);
        // batched bto/bti for this group (coalesced), broadcast by shuffle
        const int gi = min(lane, gn - 1);
        const float btv_v = bto[bbase + g0 + gi];
        const int bti_v = bti[bbase + g0 + gi];
        float keep = 0.f;

        for (int i = 0; i < gn; ++i) {
            const int r = g0 + i;
            const float c0 = p0v, c1 = p1v;
            if (r + 1 < r1) {
                p0v = base[(size_t)(r + 1) * ND + lane];
                p1v = (lane < ND - 64) ? base[(size_t)(r + 1) * ND + 64 + lane]
                                       : -1e30f;
            }
            // softmax over positions 4..84
            float x0 = (lane >= 4) ? c0 : -1e30f;
            float mx = fmaxf(x0, c1);
            for (int d = 1; d < 64; d <<= 1) mx = fmaxf(mx, __shfl_xor(mx, d, 64));
            float e = 0.f;
            if (lane >= 4) e += __expf(x0 - mx);
            if (lane < ND - 64) e += __expf(c1 - mx);
            for (int d = 1; d < 64; d <<= 1) e += __shfl_xor(e, d, 64);
            const float lse = mx + __logf(e);

            const float btv = __shfl(btv_v, i, 64);
            const int o = __shfl(bti_v, i, 64);
            const bool pos = (btv >= THRESH_F);
            const int lbl = pos ? (tl[o] + 1) : 0;
            const int idx = 4 + lbl;  // 4..84
            const float val =
                (idx < 64) ? __shfl(c0, idx, 64) : __shfl(c1, idx - 64, 64);
            const float ce = lse - val;  // wave-uniform
            const float lrv = pos ? 0.f : ce;
            if (i == lane) keep = lrv;

            if (pos) {
                acc_ce += ce;
                acc_np += 1;
                const float4 pr = *(const float4*)(priors + (size_t)r * 4);
                const float mx0 = tb[o * 4 + 0], my0 = tb[o * 4 + 1];
                const float mx1 = tb[o * 4 + 2], my1 = tb[o * 4 + 3];
                const float lt0 = ((mx0 + mx1) * 0.5f - pr.x) / (VAR0_F * pr.z);
                const float lt1 = ((my0 + my1) * 0.5f - pr.y) / (VAR0_F * pr.w);
                const float lt2 = __logf((mx1 - mx0) / pr.z) / VAR1_F;
                const float lt3 = __logf((my1 - my0) / pr.w) / VAR1_F;
                const float ltv[4] = {lt0, lt1, lt2, lt3};
                for (int j = 0; j < 4; ++j) {
                    const float d = __shfl(c0, j, 64) - ltv[j];
                    const float ad = fabsf(d);
                    acc_ll += (ad < 1.f) ? 0.5f * d * d : (ad - 0.5f);
                }
            }
        }
        if (lane < gn) lr[bbase + g0 + lane] = keep;
    }
    if (lane == 0) {
        if (acc_ll != 0.f) atomicAdd(&acc[0], acc_ll);
        if (acc_ce != 0.f) atomicAdd(&acc[1], acc_ce);
        if (acc_np) atomicAdd(&npos[b], acc_np);
    }
}

// ---------------------------------------------------------------- select
// per b: radix-select K-th largest loss_rank T (values >= 0 so uint-monotone);
// negatives-sum = sum(v > T) + (K - cnt(v > T)) * T. Exact under ties.
// 1024 threads, per-wave private LDS histograms, wave-parallel suffix scan.
__global__ __launch_bounds__(1024) void k_select(
    const float* __restrict__ lrk, const int* __restrict__ npos,
    float* __restrict__ acc) {
    const int b = blockIdx.x;
    const float* row = lrk + (size_t)b * NP;
    const int tid = threadIdx.x;
    const int lane = tid & 63;
    const int wid = tid >> 6;  // 0..15

    __shared__ unsigned whist[16][256];
    __shared__ unsigned chist[256];
    __shared__ int sh_bucket, sh_knew;
    __shared__ float wsum[16];
    __shared__ int wcnt[16];

    const int K0 = min(npos[b] * NEGPOS_I, NP);
    int k = K0;
    unsigned prefix = 0;

    for (int shift = 24; shift >= 0; shift -= 8) {
        // zero private hist (each thread zeros 4 entries of its wave's hist)
        for (int j = lane; j < 256; j += 64) whist[wid][j] = 0;
        __syncthreads();
        const unsigned mask_hi = (shift == 24) ? 0u : (0xFFFFFFFFu << (shift + 8));
        for (int i = tid; i < NP; i += 1024) {
            unsigned v = __float_as_uint(row[i]);
            if ((v & mask_hi) == (prefix & mask_hi))
                atomicAdd(&whist[wid][(v >> shift) & 0xFFu], 1u);
        }
        __syncthreads();
        if (tid < 256) {
            unsigned t = 0;
            for (int w = 0; w < 16; ++w) t += whist[w][tid];
            chist[tid] = t;
        }
        __syncthreads();
        if (tid < 64) {
            const unsigned c0 = chist[4 * lane + 0];
            const unsigned c1 = chist[4 * lane + 1];
            const unsigned c2 = chist[4 * lane + 2];
            const unsigned c3 = chist[4 * lane + 3];
            const unsigned g = c0 + c1 + c2 + c3;
            unsigned T = g;  // inclusive suffix sum over lanes (from top)
            for (int d = 1; d < 64; d <<= 1) {
                unsigned t = __shfl_down(T, d, 64);
                if (lane + d < 64) T += t;
            }
            const unsigned E = T - g;  // strict suffix
            const bool hit = (E < (unsigned)k) && ((unsigned)k <= T);
            unsigned long long msk = __ballot(hit);
            int wl = __ffsll(msk) - 1;
            if (lane == wl) {
                unsigned cum = E;
                int bsel = 4 * lane;
                int kn = k;
                const unsigned cc[4] = {c3, c2, c1, c0};
                for (int j = 0; j < 4; ++j) {
                    if (cum + cc[j] >= (unsigned)k) {
                        bsel = 4 * lane + 3 - j;
                        kn = k - (int)cum;
                        break;
                    }
                    cum += cc[j];
                }
                sh_bucket = bsel;
                sh_knew = kn;
            }
        }
        __syncthreads();
        prefix |= ((unsigned)sh_bucket) << shift;
        k = sh_knew;
        __syncthreads();
    }
    const float T = __uint_as_float(prefix);

    float msum = 0.f;
    int mcnt = 0;
    for (int i = tid; i < NP; i += 1024) {
        float v = row[i];
        if (__float_as_uint(v) > prefix) { msum += v; mcnt++; }
    }
    for (int s = 32; s > 0; s >>= 1) {
        msum += __shfl_down(msum, s, 64);
        mcnt += __shfl_down(mcnt, s, 64);
    }
    if (lane == 0) { wsum[wid] = msum; wcnt[wid] = mcnt; }
    __syncthreads();
    if (tid == 0) {
        float tot = 0.f;
        int cnt = 0;
        for (int w = 0; w < 16; ++w) { tot += wsum[w]; cnt += wcnt[w]; }
        float negsum = tot + (float)(K0 - cnt) * T;
        atomicAdd(&acc[1], negsum);
    }
}

// ---------------------------------------------------------------- final
__global__ void k_final(const int* __restrict__ npos,
                        const float* __restrict__ acc,
                        float* __restrict__ out) {
    if (threadIdx.x == 0 && blockIdx.x == 0) {
        int n = 0;
        for (int b = 0; b < NB; ++b) n += npos[b];
        const float N = (float)n;
        out[0] = acc[0] / N;
        out[1] = acc[1] / N;
    }
}

extern "C" void kernel_launch(void* const* d_in, const int* in_sizes, int n_in,
                              void* d_out, int out_size, void* d_ws, size_t ws_size,
                              hipStream_t stream) {
    const float* pred   = (const float*)d_in[0];
    const float* tboxes = (const float*)d_in[1];
    const int*   tlabels = (const int*)d_in[2];
    const float* priors = (const float*)d_in[3];
    float* out = (float*)d_out;

    char* w = (char*)d_ws;
    float* bto = (float*)w;                                   // BPCNT f32
    int*   bti = (int*)(w + 4ull * BPCNT);                    // BPCNT i32
    float* lrk = (float*)(w + 8ull * BPCNT);                  // BPCNT f32
    unsigned long long* bpk =
        (unsigned long long*)(w + 12ull * BPCNT);             // NB*NO u64
    int* npos = (int*)(w + 12ull * BPCNT + 8ull * NB * NO);   // NB i32
    float* acc = (float*)(w + 12ull * BPCNT + 8ull * NB * NO + 4ull * NB);

    k_init<<<dim3(2), dim3(256), 0, stream>>>(bpk, npos, acc);
    k_match<<<dim3((NP + 255) / 256, NB), dim3(256), 0, stream>>>(
        tboxes, priors, bto, bti, bpk);
    k_scatter<<<dim3(1), dim3(64), 0, stream>>>(bpk, bto, bti);
    k_main<<<dim3(WPB / 4, NB), dim3(256), 0, stream>>>(
        pred, tboxes, tlabels, priors, bto, bti, lrk, npos, acc);
    k_select<<<dim3(NB), dim3(1024), 0, stream>>>(lrk, npos, acc);
    k_final<<<dim3(1), dim3(1), 0, stream>>>(npos, acc, out);
}

// Round 3
// 341.066 us; speedup vs baseline: 1.4912x; 1.3353x over previous
//
#include <hip/hip_runtime.h>
#include <math.h>

#define NB 32
#define NP 24656
#define NO 16
#define NC 81
#define ND 85   // 4 + NC
#define THRESH_F 0.5f
#define NEGPOS_I 3
#define VAR0_F 0.1f
#define VAR1_F 0.2f
#define NEG_HUGE -1e30f

#define BPCNT (NB * NP)

// ---------------------------------------------------------------- init
__global__ void k_init(unsigned long long* __restrict__ bpk,
                       int* __restrict__ npos,
                       float* __restrict__ accB) {
    int t = blockIdx.x * blockDim.x + threadIdx.x;
    if (t < NB * NO) bpk[t] = 0ull;
    if (t < NB) npos[t] = 0;
    if (t < 2 * NB) accB[t] = 0.f;
}

// ---------------------------------------------------------------- match
__global__ __launch_bounds__(256) void k_match(
    const float* __restrict__ tboxes, const float* __restrict__ priors,
    float* __restrict__ bto, int* __restrict__ bti,
    unsigned long long* __restrict__ bpk) {
    const int b = blockIdx.y;
    const int p = blockIdx.x * 256 + threadIdx.x;
    const int lane = threadIdx.x & 63;
    __shared__ float tb[NO * 4];
    if (threadIdx.x < NO * 4) tb[threadIdx.x] = tboxes[b * NO * 4 + threadIdx.x];
    __syncthreads();

    const bool valid = (p < NP);
    float4 pr = make_float4(0.f, 0.f, 1.f, 1.f);
    if (valid) pr = *(const float4*)(priors + (size_t)p * 4);
    const float pl = pr.x - pr.z * 0.5f, pt = pr.y - pr.w * 0.5f;
    const float prr = pr.x + pr.z * 0.5f, pb = pr.y + pr.w * 0.5f;
    const float parea = (prr - pl) * (pb - pt);

    float bestv = -1.f;
    int besti = 0;
    for (int o = 0; o < NO; ++o) {
        const float al = tb[o * 4 + 0], at = tb[o * 4 + 1];
        const float ar = tb[o * 4 + 2], ab = tb[o * 4 + 3];
        float iw = fminf(ar, prr) - fmaxf(al, pl); iw = fmaxf(iw, 0.f);
        float ih = fminf(ab, pb) - fmaxf(at, pt); ih = fmaxf(ih, 0.f);
        const float inter = iw * ih;
        const float aarea = (ar - al) * (ab - at);
        float iou = inter / (aarea + parea - inter);
        if (!valid) iou = -1.f;
        if (iou > bestv) { bestv = iou; besti = o; }

        float m = iou;
        for (int d = 1; d < 64; d <<= 1) m = fmaxf(m, __shfl_xor(m, d, 64));
        if (m >= 0.f) {
            unsigned long long msk = __ballot(iou == m);
            int lam = __ffsll(msk) - 1;
            int pw = blockIdx.x * 256 + (threadIdx.x & ~63) + lam;
            if (lane == 0) {
                unsigned long long key =
                    ((unsigned long long)__float_as_uint(m) << 32) |
                    (unsigned long long)(0xFFFFFFFFu - (unsigned)pw);
                atomicMax(&bpk[b * NO + o], key);
            }
        }
    }
    if (valid) {
        bto[(size_t)b * NP + p] = bestv;
        bti[(size_t)b * NP + p] = besti;
    }
}

// ---------------------------------------------------------------- scatter
__global__ void k_scatter(const unsigned long long* __restrict__ bpk,
                          float* __restrict__ bto, int* __restrict__ bti) {
    int b = blockIdx.x * blockDim.x + threadIdx.x;
    if (b >= NB) return;
    for (int o = 0; o < NO; ++o) {
        unsigned long long key = bpk[b * NO + o];
        int p = (int)(0xFFFFFFFFu - (unsigned)(key & 0xFFFFFFFFull));
        bto[(size_t)b * NP + p] = 2.0f;
        bti[(size_t)b * NP + p] = o;
    }
}

// ---------------------------------------------------------------- main fused
// Lane-per-row, register-resident row via 22 ALIGNED float4 loads
// (A = 21r + r/4, component offset c0 = r&3; edges neutralized to -1e30).
// Online softmax over 21 conf chunks. No LDS, no cross-lane in hot path.
__global__ __launch_bounds__(256) void k_main(
    const float* __restrict__ pred, const float* __restrict__ tboxes,
    const int* __restrict__ tlabels, const float* __restrict__ priors,
    const float* __restrict__ bto, const int* __restrict__ bti,
    float* __restrict__ lr, int* __restrict__ npos, float* __restrict__ accB) {
    const int b = blockIdx.y;
    const int tid = threadIdx.x;
    const int p = blockIdx.x * 256 + tid;
    const bool valid = (p < NP);
    const int r = valid ? p : (NP - 1);

    const float* base = pred + (size_t)b * NP * ND;  // 16B-aligned (NP%4==0)
    const int A = 21 * r + (r >> 2);
    const int c0 = r & 3;
    const float4* vp = (const float4*)base + A;

    const float4 v0 = vp[0];
    float4 v1 = vp[1];
    const float4 v1o = v1;
    // background logit dw[c0+4]
    const float bg = (c0 == 0) ? v1.x : (c0 == 1) ? v1.y : (c0 == 2) ? v1.z : v1.w;
    // neutralize leading invalid slots (j < c0+4) in v1
    v1.x = (c0 >= 1) ? NEG_HUGE : v1.x;
    v1.y = (c0 >= 2) ? NEG_HUGE : v1.y;
    v1.z = (c0 >= 3) ? NEG_HUGE : v1.z;

    float m = NEG_HUGE, s = 0.f;
    float4 c = v1;
#pragma unroll
    for (int k = 2; k <= 21; ++k) {
        float4 nx = vp[k];
        if (k == 21) {  // trailing invalid: dw[85+t] invalid iff t >= c0
            nx.y = (c0 <= 0) ? NEG_HUGE : nx.y;
            nx.z = (c0 <= 1) ? NEG_HUGE : nx.z;
            nx.w = (c0 <= 2) ? NEG_HUGE : nx.w;
        }
        const float cm = fmaxf(fmaxf(c.x, c.y), fmaxf(c.z, c.w));
        const float mn = fmaxf(m, cm);
        const float sc = __expf(m - mn);
        s = s * sc + (__expf(c.x - mn) + __expf(c.y - mn)) +
            (__expf(c.z - mn) + __expf(c.w - mn));
        m = mn;
        c = nx;
    }
    {
        const float cm = fmaxf(fmaxf(c.x, c.y), fmaxf(c.z, c.w));
        const float mn = fmaxf(m, cm);
        const float sc = __expf(m - mn);
        s = s * sc + (__expf(c.x - mn) + __expf(c.y - mn)) +
            (__expf(c.z - mn) + __expf(c.w - mn));
        m = mn;
    }
    const float lse = m + __logf(s);

    float btv = 0.f;
    int o = 0;
    if (valid) {
        btv = bto[(size_t)b * NP + p];
        o = bti[(size_t)b * NP + p];
    }
    const bool pos = valid && (btv >= THRESH_F);
    if (valid) lr[(size_t)b * NP + p] = pos ? 0.f : (lse - bg);

    float my_ll = 0.f, my_ce = 0.f;
    int my_np = 0;
    if (pos) {
        my_np = 1;
        const int lbl = tlabels[b * NO + o] + 1;
        const float val = base[(size_t)r * ND + 4 + lbl];  // L1/L2 hit
        my_ce = lse - val;
        const float4 pr = *((const float4*)priors + r);
        const float tx0 = tboxes[(b * NO + o) * 4 + 0];
        const float ty0 = tboxes[(b * NO + o) * 4 + 1];
        const float tx1 = tboxes[(b * NO + o) * 4 + 2];
        const float ty1 = tboxes[(b * NO + o) * 4 + 3];
        // loc = dw[c0..c0+3] selected from v0 / pre-neutralize v1o
        const float l0 = (c0 == 0) ? v0.x : (c0 == 1) ? v0.y : (c0 == 2) ? v0.z : v0.w;
        const float l1 = (c0 == 0) ? v0.y : (c0 == 1) ? v0.z : (c0 == 2) ? v0.w : v1o.x;
        const float l2 = (c0 == 0) ? v0.z : (c0 == 1) ? v0.w : (c0 == 2) ? v1o.x : v1o.y;
        const float l3 = (c0 == 0) ? v0.w : (c0 == 1) ? v1o.x : (c0 == 2) ? v1o.y : v1o.z;
        const float g0 = ((tx0 + tx1) * 0.5f - pr.x) / (VAR0_F * pr.z);
        const float g1 = ((ty0 + ty1) * 0.5f - pr.y) / (VAR0_F * pr.w);
        const float g2 = __logf((tx1 - tx0) / pr.z) / VAR1_F;
        const float g3 = __logf((ty1 - ty0) / pr.w) / VAR1_F;
        float dd, ad;
        dd = l0 - g0; ad = fabsf(dd); my_ll += (ad < 1.f) ? 0.5f * dd * dd : (ad - 0.5f);
        dd = l1 - g1; ad = fabsf(dd); my_ll += (ad < 1.f) ? 0.5f * dd * dd : (ad - 0.5f);
        dd = l2 - g2; ad = fabsf(dd); my_ll += (ad < 1.f) ? 0.5f * dd * dd : (ad - 0.5f);
        dd = l3 - g3; ad = fabsf(dd); my_ll += (ad < 1.f) ? 0.5f * dd * dd : (ad - 0.5f);
    }
    // one wave-reduce per wave, then per-b atomics (<=388 adds/address)
    for (int d2 = 1; d2 < 64; d2 <<= 1) {
        my_ll += __shfl_xor(my_ll, d2, 64);
        my_ce += __shfl_xor(my_ce, d2, 64);
        my_np += __shfl_xor(my_np, d2, 64);
    }
    if ((tid & 63) == 0) {
        if (my_ll != 0.f) atomicAdd(&accB[b * 2 + 0], my_ll);
        if (my_ce != 0.f) atomicAdd(&accB[b * 2 + 1], my_ce);
        if (my_np) atomicAdd(&npos[b], my_np);
    }
}

// ---------------------------------------------------------------- select
__global__ __launch_bounds__(1024) void k_select(
    const float* __restrict__ lrk, const int* __restrict__ npos,
    float* __restrict__ accB) {
    const int b = blockIdx.x;
    const float* row = lrk + (size_t)b * NP;
    const int tid = threadIdx.x;
    const int lane = tid & 63;
    const int wid = tid >> 6;

    __shared__ unsigned whist[16][256];
    __shared__ unsigned chist[256];
    __shared__ int sh_bucket, sh_knew;
    __shared__ float wsum[16];
    __shared__ int wcnt[16];

    const int K0 = min(npos[b] * NEGPOS_I, NP);
    int k = K0;
    unsigned prefix = 0;

    for (int shift = 24; shift >= 0; shift -= 8) {
        for (int j = lane; j < 256; j += 64) whist[wid][j] = 0;
        __syncthreads();
        const unsigned mask_hi = (shift == 24) ? 0u : (0xFFFFFFFFu << (shift + 8));
        for (int i = tid; i < NP; i += 1024) {
            unsigned v = __float_as_uint(row[i]);
            if ((v & mask_hi) == (prefix & mask_hi))
                atomicAdd(&whist[wid][(v >> shift) & 0xFFu], 1u);
        }
        __syncthreads();
        if (tid < 256) {
            unsigned t = 0;
            for (int w = 0; w < 16; ++w) t += whist[w][tid];
            chist[tid] = t;
        }
        __syncthreads();
        if (tid < 64) {
            const unsigned cA = chist[4 * lane + 0];
            const unsigned cB = chist[4 * lane + 1];
            const unsigned cC = chist[4 * lane + 2];
            const unsigned cD = chist[4 * lane + 3];
            const unsigned g = cA + cB + cC + cD;
            unsigned T = g;
            for (int d = 1; d < 64; d <<= 1) {
                unsigned t = __shfl_down(T, d, 64);
                if (lane + d < 64) T += t;
            }
            const unsigned E = T - g;
            const bool hit = (E < (unsigned)k) && ((unsigned)k <= T);
            unsigned long long msk = __ballot(hit);
            int wl = __ffsll(msk) - 1;
            if (lane == wl) {
                unsigned cum = E;
                int bsel = 4 * lane;
                int kn = k;
                const unsigned cc[4] = {cD, cC, cB, cA};
                for (int j = 0; j < 4; ++j) {
                    if (cum + cc[j] >= (unsigned)k) {
                        bsel = 4 * lane + 3 - j;
                        kn = k - (int)cum;
                        break;
                    }
                    cum += cc[j];
                }
                sh_bucket = bsel;
                sh_knew = kn;
            }
        }
        __syncthreads();
        prefix |= ((unsigned)sh_bucket) << shift;
        k = sh_knew;
        __syncthreads();
    }
    const float T = __uint_as_float(prefix);

    float msum = 0.f;
    int mcnt = 0;
    for (int i = tid; i < NP; i += 1024) {
        float v = row[i];
        if (__float_as_uint(v) > prefix) { msum += v; mcnt++; }
    }
    for (int s = 32; s > 0; s >>= 1) {
        msum += __shfl_down(msum, s, 64);
        mcnt += __shfl_down(mcnt, s, 64);
    }
    if (lane == 0) { wsum[wid] = msum; wcnt[wid] = mcnt; }
    __syncthreads();
    if (tid == 0) {
        float tot = 0.f;
        int cnt = 0;
        for (int w = 0; w < 16; ++w) { tot += wsum[w]; cnt += wcnt[w]; }
        atomicAdd(&accB[b * 2 + 1], tot + (float)(K0 - cnt) * T);
    }
}

// ---------------------------------------------------------------- final
__global__ void k_final(const int* __restrict__ npos,
                        const float* __restrict__ accB,
                        float* __restrict__ out) {
    if (threadIdx.x == 0 && blockIdx.x == 0) {
        int n = 0;
        float a0 = 0.f, a1 = 0.f;
        for (int b = 0; b < NB; ++b) {
            n += npos[b];
            a0 += accB[b * 2 + 0];
            a1 += accB[b * 2 + 1];
        }
        const float N = (float)n;
        out[0] = a0 / N;
        out[1] = a1 / N;
    }
}

extern "C" void kernel_launch(void* const* d_in, const int* in_sizes, int n_in,
                              void* d_out, int out_size, void* d_ws, size_t ws_size,
                              hipStream_t stream) {
    const float* pred   = (const float*)d_in[0];
    const float* tboxes = (const float*)d_in[1];
    const int*   tlabels = (const int*)d_in[2];
    const float* priors = (const float*)d_in[3];
    float* out = (float*)d_out;

    char* w = (char*)d_ws;
    float* bto = (float*)w;                                   // BPCNT f32
    int*   bti = (int*)(w + 4ull * BPCNT);                    // BPCNT i32
    float* lrk = (float*)(w + 8ull * BPCNT);                  // BPCNT f32
    unsigned long long* bpk =
        (unsigned long long*)(w + 12ull * BPCNT);             // NB*NO u64
    int* npos = (int*)(w + 12ull * BPCNT + 8ull * NB * NO);   // NB i32
    float* accB = (float*)(w + 12ull * BPCNT + 8ull * NB * NO + 4ull * NB); // NB*2

    k_init<<<dim3(2), dim3(256), 0, stream>>>(bpk, npos, accB);
    k_match<<<dim3((NP + 255) / 256, NB), dim3(256), 0, stream>>>(
        tboxes, priors, bto, bti, bpk);
    k_scatter<<<dim3(1), dim3(64), 0, stream>>>(bpk, bto, bti);
    k_main<<<dim3((NP + 255) / 256, NB), dim3(256), 0, stream>>>(
        pred, tboxes, tlabels, priors, bto, bti, lrk, npos, accB);
    k_select<<<dim3(NB), dim3(1024), 0, stream>>>(lrk, npos, accB);
    k_final<<<dim3(1), dim3(1), 0, stream>>>(npos, accB, out);
}